// Round 12
// baseline (144.856 us; speedup 1.0000x reference)
//
#include <hip/hip_runtime.h>

#define BATCH 2
#define SEQ 2048
#define DMODEL 768
#define NH 12
#define DHEAD 64
#define D3 (3 * DMODEL)  // 2304

typedef float f32x4 __attribute__((ext_vector_type(4)));
typedef __bf16 bf16x8 __attribute__((ext_vector_type(8)));
typedef __bf16 bf16x4 __attribute__((ext_vector_type(4)));

#define NEG_INF (-__builtin_inff())
#define SCL 0.18033688011112042f  // (1/sqrt(64)) * log2(e), folded into W_q/b_q

__device__ __forceinline__ void g2l16(const void* g, void* l) {
    __builtin_amdgcn_global_load_lds(
        (const __attribute__((address_space(1))) void*)g,
        (__attribute__((address_space(3))) void*)l,
        16, 0, 0);
}

__device__ __forceinline__ unsigned pack_bf16(float lo, float hi) {
    unsigned a = __builtin_bit_cast(unsigned short, (__bf16)lo);
    unsigned b = __builtin_bit_cast(unsigned short, (__bf16)hi);
    return a | (b << 16);
}

// ---------------- fused f32 -> bf16 convert (counts in float4 units) ----------------
#define XQ 786432   // 2*2048*768 / 4
#define WQQ 442368  // 2304*768 / 4
#define WOQ 147456  // 768*768 / 4
#define WQROWS 147456  // float4 idx bound for w_qkv rows < 768
__global__ __launch_bounds__(256) void cvt3_kernel(const float* __restrict__ X,
                                                   const float* __restrict__ Wq,
                                                   const float* __restrict__ Wo,
                                                   __bf16* __restrict__ Xb,
                                                   __bf16* __restrict__ Wqb,
                                                   __bf16* __restrict__ Wob) {
    int i = blockIdx.x * 256 + threadIdx.x;
    const float* s; __bf16* d; int k;
    float scl = 1.0f;
    if (i < XQ)            { s = X;  d = Xb;  k = i; }
    else if (i < XQ + WQQ) { s = Wq; d = Wqb; k = i - XQ; if (k < WQROWS) scl = SCL; }
    else                   { s = Wo; d = Wob; k = i - XQ - WQQ; }
    float4 v = ((const float4*)s)[k];
    bf16x4 o;
    o[0] = (__bf16)(v.x * scl); o[1] = (__bf16)(v.y * scl);
    o[2] = (__bf16)(v.z * scl); o[3] = (__bf16)(v.w * scl);
    ((bf16x4*)d)[k] = o;
}

// ---------------- padding mask -> lengths; also emit scaled b_qkv copy ----------------
__global__ __launch_bounds__(256) void lens_kernel(const unsigned char* __restrict__ mask,
                                                   const float* __restrict__ bq,
                                                   float* __restrict__ bqs,
                                                   int* __restrict__ lens) {
    __shared__ int nz_s;
    __shared__ int cnt[2];
    if (threadIdx.x == 0) { nz_s = 0; cnt[0] = 0; cnt[1] = 0; }
    __syncthreads();
    for (int i = threadIdx.x; i < D3; i += 256)
        bqs[i] = bq[i] * (i < DMODEL ? SCL : 1.0f);
    uint4 mv = ((const uint4*)mask)[threadIdx.x];  // covers bytes [0,4096)
    if (mv.x | mv.y | mv.z | mv.w) nz_s = 1;
    __syncthreads();
    int c0 = 0, c1 = 0;
    if (nz_s) {  // bool layout
        for (int s = threadIdx.x; s < SEQ; s += 256) {
            c0 += (mask[s] != 0);
            c1 += (mask[SEQ + s] != 0);
        }
    } else {     // int32 layout
        const int* mi = (const int*)mask;
        for (int s = threadIdx.x; s < SEQ; s += 256) {
            c0 += (mi[s] != 0);
            c1 += (mi[SEQ + s] != 0);
        }
    }
    atomicAdd(&cnt[0], c0);
    atomicAdd(&cnt[1], c1);
    __syncthreads();
    if (threadIdx.x == 0) {
        lens[0] = SEQ - cnt[0];
        lens[1] = SEQ - cnt[1];
    }
}

// -------- QKV GEMM: split outputs: Qd natural, Kd per-head dense, Vp tiled-transposed --
__global__ __launch_bounds__(256) void gemm_qkv(const __bf16* __restrict__ A,
                                                const __bf16* __restrict__ Bw,
                                                const float* __restrict__ bias,
                                                __bf16* __restrict__ Qd,
                                                __bf16* __restrict__ Kd,
                                                __bf16* __restrict__ Vp) {
    const int K = 768;
    __shared__ __align__(16) __bf16 As[128][64];
    __shared__ __align__(16) __bf16 Bs[128][64];
    const int tid = threadIdx.x;
    const int wave = tid >> 6, lane = tid & 63;
    const int bm = blockIdx.x * 128, bn = blockIdx.y * 128;
    const int wr = (wave >> 1) * 64, wc = (wave & 1) * 64;
    const int l15 = lane & 15, lg = lane >> 4;
    const int rsub = lane >> 3;
    const int csub = (((lane & 7) ^ rsub) * 8);
    const int rswz = (l15 & 7) * 8;

    f32x4 acc[4][4] = {};

    for (int kt = 0; kt < K; kt += 64) {
#pragma unroll
        for (int it = 0; it < 4; ++it) {
            int c = it * 4 + wave;
            int row = c * 8 + rsub;
            g2l16(A + (size_t)(bm + row) * K + kt + csub, &As[0][0] + c * 512);
            g2l16(Bw + (size_t)(bn + row) * K + kt + csub, &Bs[0][0] + c * 512);
        }
        __syncthreads();
#pragma unroll
        for (int kk = 0; kk < 2; ++kk) {
            bf16x8 af[4], bfr[4];
            const int col = (kk * 32 + lg * 8) ^ rswz;
#pragma unroll
            for (int m = 0; m < 4; ++m)
                af[m] = *(const bf16x8*)(&As[0][0] + (wr + m * 16 + l15) * 64 + col);
#pragma unroll
            for (int n = 0; n < 4; ++n)
                bfr[n] = *(const bf16x8*)(&Bs[0][0] + (wc + n * 16 + l15) * 64 + col);
#pragma unroll
            for (int m = 0; m < 4; ++m)
#pragma unroll
                for (int n = 0; n < 4; ++n)
                    acc[m][n] = __builtin_amdgcn_mfma_f32_16x16x32_bf16(af[m], bfr[n], acc[m][n], 0, 0, 0);
        }
        __syncthreads();
    }

#pragma unroll
    for (int n = 0; n < 4; ++n) {
        int col = bn + wc + n * 16 + l15;
        float bv = bias[col];
#pragma unroll
        for (int m = 0; m < 4; ++m) {
#pragma unroll
            for (int j = 0; j < 4; ++j) {
                int row = bm + wr + m * 16 + lg * 4 + j;
                __bf16 v = (__bf16)(acc[m][n][j] + bv);
                if (bn < 768) {
                    Qd[(size_t)row * 768 + col] = v;
                } else if (bn < 1536) {
                    int kc = col - 768;
                    int hh = kc >> 6, dh = kc & 63;
                    int bb = row >> 11, key = row & 2047;
                    Kd[(size_t)(bb * NH + hh) * 131072 + key * 64 + dh] = v;
                } else {
                    int vc = col - 1536;
                    int hh = vc >> 6, dh = vc & 63;
                    int bb = row >> 11, key = row & 2047;
                    Vp[(size_t)(bb * NH + hh) * 131072 + (key >> 6) * 4096 + dh * 64 + (key & 63)] = v;
                }
            }
        }
    }
}

// ---------------- out-projection GEMM (validated round 3) ----------------
__global__ __launch_bounds__(256) void gemm_out(const __bf16* __restrict__ A,
                                                const __bf16* __restrict__ Bw,
                                                const float* __restrict__ bias,
                                                float* __restrict__ Cout,
                                                int M, int N, int K) {
    __shared__ __align__(16) __bf16 As[128][64];
    __shared__ __align__(16) __bf16 Bs[128][64];
    const int tid = threadIdx.x;
    const int wave = tid >> 6, lane = tid & 63;
    const int bm = blockIdx.x * 128, bn = blockIdx.y * 128;
    const int wr = (wave >> 1) * 64, wc = (wave & 1) * 64;
    const int l15 = lane & 15, lg = lane >> 4;
    const int rsub = lane >> 3;
    const int csub = (((lane & 7) ^ rsub) * 8);
    const int rswz = (l15 & 7) * 8;

    f32x4 acc[4][4] = {};

    for (int kt = 0; kt < K; kt += 64) {
#pragma unroll
        for (int it = 0; it < 4; ++it) {
            int c = it * 4 + wave;
            int row = c * 8 + rsub;
            g2l16(A + (size_t)(bm + row) * K + kt + csub, &As[0][0] + c * 512);
            g2l16(Bw + (size_t)(bn + row) * K + kt + csub, &Bs[0][0] + c * 512);
        }
        __syncthreads();
#pragma unroll
        for (int kk = 0; kk < 2; ++kk) {
            bf16x8 af[4], bfr[4];
            const int col = (kk * 32 + lg * 8) ^ rswz;
#pragma unroll
            for (int m = 0; m < 4; ++m)
                af[m] = *(const bf16x8*)(&As[0][0] + (wr + m * 16 + l15) * 64 + col);
#pragma unroll
            for (int n = 0; n < 4; ++n)
                bfr[n] = *(const bf16x8*)(&Bs[0][0] + (wc + n * 16 + l15) * 64 + col);
#pragma unroll
            for (int m = 0; m < 4; ++m)
#pragma unroll
                for (int n = 0; n < 4; ++n)
                    acc[m][n] = __builtin_amdgcn_mfma_f32_16x16x32_bf16(af[m], bfr[n], acc[m][n], 0, 0, 0);
        }
        __syncthreads();
    }

#pragma unroll
    for (int n = 0; n < 4; ++n) {
        int col = bn + wc + n * 16 + l15;
        float bv = bias[col];
#pragma unroll
        for (int m = 0; m < 4; ++m) {
#pragma unroll
            for (int j = 0; j < 4; ++j) {
                int row = bm + wr + m * 16 + lg * 4 + j;
                Cout[(size_t)row * N + col] = acc[m][n][j] + bv;
            }
        }
    }
}

// ---- normalize accumulated rows (q >= 1024): AOb = Oacc / Lacc, bf16 -----------------
__global__ __launch_bounds__(256) void norml_kernel(const float* __restrict__ Oacc,
                                                    const float* __restrict__ Lacc,
                                                    __bf16* __restrict__ AOb) {
    int i = blockIdx.x * 256 + threadIdx.x;   // over 2048 rows * 192 col-quads
    int cq = i % 192, row = i / 192;          // row = b*1024 + qr
    int col = cq * 4;
    float linv = 1.0f / Lacc[row * NH + (col >> 6)];
    f32x4 v = ((const f32x4*)Oacc)[i];
    int b = row >> 10, qr = row & 1023;
    bf16x4 o;
    o[0] = (__bf16)(v[0] * linv); o[1] = (__bf16)(v[1] * linv);
    o[2] = (__bf16)(v[2] * linv); o[3] = (__bf16)(v[3] * linv);
    *(bf16x4*)(AOb + ((size_t)(b * SEQ + 1024 + qr)) * DMODEL + col) = o;
}

// ------- flash attention: key-split slices, 1 wave/block, 2x16-row q-subtiles ---------
// Static-max softmax => slice partials (O,l) are directly summable. Classes per bh:
//  p<32: 1 slice (<=16 tiles, writes AOb directly);  p in [32,48): 2 slices;
//  p>=48: 4 slices. Multi-slice waves atomically accumulate f32 into Oacc/Lacc
//  (rows q>=1024 only), combined by norml_kernel. Shuffle-free P->PV (permuted K),
//  folded scale, dense Kd rows / tiled Vp, XCD-pinned heads, heavy-first.
__global__ __launch_bounds__(64) void attn_kernel(const __bf16* __restrict__ Qd,
                                                  const __bf16* __restrict__ Kd,
                                                  const int* __restrict__ lens,
                                                  const __bf16* __restrict__ Vp,
                                                  __bf16* __restrict__ Out,
                                                  float* __restrict__ Oacc,
                                                  float* __restrict__ Lacc) {
    const int lane = threadIdx.x;
    const int l15 = lane & 15, lg = lane >> 4;
    const int blk = blockIdx.x;
    const int xcd = blk & 7, idx = blk >> 3;   // idx 0..383
    const int hl = idx % 3, item = idx / 3;    // item 0..127
    int p, s, ns;
    if (item < 32)      { p = 31 - item;            s = 0;            ns = 1; }
    else if (item < 64) { int t = item - 32; p = 32 + (t >> 1); s = t & 1; ns = 2; }
    else                { int t = item - 64; p = 48 + (t >> 2); s = t & 3; ns = 4; }
    const int bh = xcd * 3 + hl;
    const int b = bh / NH, h = bh % NH;
    const int len = lens[b];
    const int q0 = p * 32;

    // permuted K row for this lane: prow = (l15>>2)*8 + (l15&3)
    const int prow = ((l15 >> 2) << 3) + (l15 & 3);
    const __bf16* kbase = Kd + (size_t)bh * 131072 + prow * 64 + lg * 8;
    const __bf16* vbase = Vp + (size_t)bh * 131072 + l15 * 64 + lg * 8;

    // Q fragments (B-operand) for both subtiles
    bf16x8 qf[2][2];
    int qcap[2];
#pragma unroll
    for (int m = 0; m < 2; ++m) {
        const __bf16* qp_ = Qd + (size_t)(b * SEQ + q0 + m * 16 + l15) * DMODEL + h * DHEAD + lg * 8;
        qf[m][0] = *(const bf16x8*)qp_;
        qf[m][1] = *(const bf16x8*)(qp_ + 32);
        int myq = q0 + m * 16 + l15;
        qcap[m] = (len - 1 < myq) ? (len - 1) : myq;
    }

    int kmax = q0 + 32;
    if (len < kmax) kmax = len;
    const int nt = (kmax + 63) >> 6;
    const int ts = (nt * s) / ns, te = (nt * (s + 1)) / ns;  // this wave's tile range

    f32x4 accO[2][4] = {};
    float l_part[2] = {0.f, 0.f};

    bf16x8 kA[2][4], kB[2][4];

    auto kload = [&](bf16x8(&kf)[2][4], int kt) {
        const int k0 = kt * 64;
#pragma unroll
        for (int n = 0; n < 4; ++n) {
            const int roff = (k0 + ((n >> 1) << 5) + ((n & 1) << 2)) * 64;
#pragma unroll
            for (int kkd = 0; kkd < 2; ++kkd)
                kf[kkd][n] = *(const bf16x8*)(kbase + roff + kkd * 32);
        }
    };

    auto compute = [&](bf16x8(&kf)[2][4], int kt) {
        const int k0 = kt * 64;
        const __bf16* vt = vbase + kt * 4096;
        bf16x8 vf[2][4];
#pragma unroll
        for (int kk = 0; kk < 2; ++kk)
#pragma unroll
            for (int n = 0; n < 4; ++n)
                vf[kk][n] = *(const bf16x8*)(vt + n * 1024 + kk * 32);

        bf16x8 pa[2][2];
#pragma unroll
        for (int m = 0; m < 2; ++m) {
            f32x4 sc[4] = {};
            __builtin_amdgcn_s_setprio(1);
#pragma unroll
            for (int n = 0; n < 4; ++n) {
                sc[n] = __builtin_amdgcn_mfma_f32_16x16x32_bf16(kf[0][n], qf[m][0], sc[n], 0, 0, 0);
                sc[n] = __builtin_amdgcn_mfma_f32_16x16x32_bf16(kf[1][n], qf[m][1], sc[n], 0, 0, 0);
            }
            __builtin_amdgcn_s_setprio(0);

            const bool full = (k0 + 63 <= q0 + m * 16) && (k0 + 63 < len);
            float psum = 0.f;
            unsigned pk[4][2];
#pragma unroll
            for (int n = 0; n < 4; ++n) {
                const int keyb = k0 + ((n >> 1) << 5) + lg * 8 + ((n & 1) << 2);
                float pv[4];
#pragma unroll
                for (int j = 0; j < 4; ++j) {
                    float e = exp2f(sc[n][j]);
                    if (!full) e = (keyb + j <= qcap[m]) ? e : 0.f;
                    pv[j] = e;
                }
                psum += (pv[0] + pv[1]) + (pv[2] + pv[3]);
                pk[n][0] = pack_bf16(pv[0], pv[1]);
                pk[n][1] = pack_bf16(pv[2], pv[3]);
            }
            l_part[m] += psum;

            uint4 u0 = {pk[0][0], pk[0][1], pk[1][0], pk[1][1]};
            uint4 u1 = {pk[2][0], pk[2][1], pk[3][0], pk[3][1]};
            pa[m][0] = __builtin_bit_cast(bf16x8, u0);
            pa[m][1] = __builtin_bit_cast(bf16x8, u1);
        }

        __builtin_amdgcn_s_setprio(1);
#pragma unroll
        for (int m = 0; m < 2; ++m)
#pragma unroll
            for (int kk = 0; kk < 2; ++kk)
#pragma unroll
                for (int n = 0; n < 4; ++n)
                    accO[m][n] = __builtin_amdgcn_mfma_f32_16x16x32_bf16(pa[m][kk], vf[kk][n], accO[m][n], 0, 0, 0);
        __builtin_amdgcn_s_setprio(0);
    };

    // ping-pong over this wave's tile slice
    kload(kA, ts);
    int kt = ts;
    for (;;) {
        if (kt + 1 < te) kload(kB, kt + 1);
        compute(kA, kt);
        ++kt; if (kt == te) break;
        if (kt + 1 < te) kload(kA, kt + 1);
        compute(kB, kt);
        ++kt; if (kt == te) break;
    }

    if (ns == 1) {
        // single slice: full normalize + direct bf16 store (rows q < 1024)
#pragma unroll
        for (int m = 0; m < 2; ++m) {
            float lp = l_part[m];
            lp += __shfl_xor(lp, 16);
            lp += __shfl_xor(lp, 32);
            float inv = 1.0f / lp;
            float inv_j[4];
#pragma unroll
            for (int j = 0; j < 4; ++j) inv_j[j] = __shfl(inv, lg * 4 + j);
#pragma unroll
            for (int n = 0; n < 4; ++n)
#pragma unroll
                for (int j = 0; j < 4; ++j) {
                    int q = q0 + m * 16 + lg * 4 + j;
                    Out[(size_t)(b * SEQ + q) * DMODEL + h * DHEAD + n * 16 + l15] =
                        (__bf16)(accO[m][n][j] * inv_j[j]);
                }
        }
    } else {
        // multi-slice: accumulate partials (rows q >= 1024)
#pragma unroll
        for (int m = 0; m < 2; ++m) {
            float lp = l_part[m];
            lp += __shfl_xor(lp, 16);
            lp += __shfl_xor(lp, 32);
            if (lg == 0) {
                int q = q0 + m * 16 + l15;
                unsafeAtomicAdd(&Lacc[(size_t)((b << 10) + (q - 1024)) * NH + h], lp);
            }
#pragma unroll
            for (int n = 0; n < 4; ++n)
#pragma unroll
                for (int j = 0; j < 4; ++j) {
                    int q = q0 + m * 16 + lg * 4 + j;
                    unsafeAtomicAdd(&Oacc[(size_t)((b << 10) + (q - 1024)) * DMODEL +
                                          h * DHEAD + n * 16 + l15],
                                    accO[m][n][j]);
                }
        }
    }
}

extern "C" void kernel_launch(void* const* d_in, const int* in_sizes, int n_in,
                              void* d_out, int out_size, void* d_ws, size_t ws_size,
                              hipStream_t stream) {
    const float* query = (const float*)d_in[0];
    const unsigned char* mask = (const unsigned char*)d_in[1];
    const float* w_qkv = (const float*)d_in[2];
    const float* b_qkv = (const float*)d_in[3];
    const float* w_out = (const float*)d_in[4];
    const float* b_out = (const float*)d_in[5];
    float* out = (float*)d_out;

    if (ws_size < 36200448ull) return;
    char* p = (char*)d_ws;
    int* lens = (int*)p;        p += 256;
    float* bqs = (float*)p;     p += 2304 * 4 + 256;
    __bf16* Xb = (__bf16*)p;    p += (size_t)4096 * 768 * 2;
    __bf16* Wqb = (__bf16*)p;   p += (size_t)2304 * 768 * 2;
    __bf16* Wob = (__bf16*)p;   p += (size_t)768 * 768 * 2;
    __bf16* Qd = (__bf16*)p;    p += (size_t)4096 * 768 * 2;
    __bf16* Kd = (__bf16*)p;    p += (size_t)4096 * 768 * 2;
    __bf16* Vp = (__bf16*)p;    p += (size_t)4096 * 768 * 2;
    __bf16* AOb = (__bf16*)p;   p += (size_t)4096 * 768 * 2;
    float* Oacc = (float*)Xb;   // 2048 rows x 768 f32 = 6.29MB, Xb dead after gemm_qkv
    float* Lacc = (float*)Wqb;  // 2048 x 12 f32 = 98KB, Wqb dead after gemm_qkv

    lens_kernel<<<1, 256, 0, stream>>>(mask, b_qkv, bqs, lens);
    cvt3_kernel<<<(XQ + WQQ + WOQ) / 256, 256, 0, stream>>>(query, w_qkv, w_out, Xb, Wqb, Wob);

    // QKV projection with split outputs (Q pre-scaled; K dense per-head; V tiled-transposed)
    gemm_qkv<<<dim3(32, 18), 256, 0, stream>>>(Xb, Wqb, bqs, Qd, Kd, Vp);

    // zero the slice accumulators (Xb/Wqb are dead now)
    hipMemsetAsync(Oacc, 0, (size_t)2048 * 768 * 4, stream);
    hipMemsetAsync(Lacc, 0, (size_t)2048 * NH * 4, stream);

    // attention: 3072 key-split waves
    attn_kernel<<<3072, 64, 0, stream>>>(Qd, Kd, lens, Vp, AOb, Oacc, Lacc);
    // combine partials for rows q >= 1024
    norml_kernel<<<1536, 256, 0, stream>>>(Oacc, Lacc, AOb);
    // output projection: [4096,768] @ [768,768]^T -> f32 d_out
    gemm_out<<<dim3(32, 6), 256, 0, stream>>>(AOb, Wob, b_out, out, 4096, 768, 768);
}

// Round 14
// 134.975 us; speedup vs baseline: 1.0732x; 1.0732x over previous
//
#include <hip/hip_runtime.h>

#define BATCH 2
#define SEQ 2048
#define DMODEL 768
#define NH 12
#define DHEAD 64
#define D3 (3 * DMODEL)  // 2304

typedef float f32x4 __attribute__((ext_vector_type(4)));
typedef __bf16 bf16x8 __attribute__((ext_vector_type(8)));
typedef __bf16 bf16x4 __attribute__((ext_vector_type(4)));

#define NEG_INF (-__builtin_inff())
#define SCL 0.18033688011112042f  // (1/sqrt(64)) * log2(e), folded into W_q/b_q

__device__ __forceinline__ void g2l16(const void* g, void* l) {
    __builtin_amdgcn_global_load_lds(
        (const __attribute__((address_space(1))) void*)g,
        (__attribute__((address_space(3))) void*)l,
        16, 0, 0);
}

__device__ __forceinline__ unsigned pack_bf16(float lo, float hi) {
    unsigned a = __builtin_bit_cast(unsigned short, (__bf16)lo);
    unsigned b = __builtin_bit_cast(unsigned short, (__bf16)hi);
    return a | (b << 16);
}

// ---------------- fused f32 -> bf16 convert (counts in float4 units) ----------------
#define XQ 786432   // 2*2048*768 / 4
#define WQQ 442368  // 2304*768 / 4
#define WOQ 147456  // 768*768 / 4
#define WQROWS 147456  // float4 idx bound for w_qkv rows < 768
__global__ __launch_bounds__(256) void cvt3_kernel(const float* __restrict__ X,
                                                   const float* __restrict__ Wq,
                                                   const float* __restrict__ Wo,
                                                   __bf16* __restrict__ Xb,
                                                   __bf16* __restrict__ Wqb,
                                                   __bf16* __restrict__ Wob) {
    int i = blockIdx.x * 256 + threadIdx.x;
    const float* s; __bf16* d; int k;
    float scl = 1.0f;
    if (i < XQ)            { s = X;  d = Xb;  k = i; }
    else if (i < XQ + WQQ) { s = Wq; d = Wqb; k = i - XQ; if (k < WQROWS) scl = SCL; }
    else                   { s = Wo; d = Wob; k = i - XQ - WQQ; }
    float4 v = ((const float4*)s)[k];
    bf16x4 o;
    o[0] = (__bf16)(v.x * scl); o[1] = (__bf16)(v.y * scl);
    o[2] = (__bf16)(v.z * scl); o[3] = (__bf16)(v.w * scl);
    ((bf16x4*)d)[k] = o;
}

// ---------------- padding mask -> lengths; also emit scaled b_qkv copy ----------------
__global__ __launch_bounds__(256) void lens_kernel(const unsigned char* __restrict__ mask,
                                                   const float* __restrict__ bq,
                                                   float* __restrict__ bqs,
                                                   int* __restrict__ lens) {
    __shared__ int nz_s;
    __shared__ int cnt[2];
    if (threadIdx.x == 0) { nz_s = 0; cnt[0] = 0; cnt[1] = 0; }
    __syncthreads();
    for (int i = threadIdx.x; i < D3; i += 256)
        bqs[i] = bq[i] * (i < DMODEL ? SCL : 1.0f);
    uint4 mv = ((const uint4*)mask)[threadIdx.x];  // covers bytes [0,4096)
    if (mv.x | mv.y | mv.z | mv.w) nz_s = 1;
    __syncthreads();
    int c0 = 0, c1 = 0;
    if (nz_s) {  // bool layout
        for (int s = threadIdx.x; s < SEQ; s += 256) {
            c0 += (mask[s] != 0);
            c1 += (mask[SEQ + s] != 0);
        }
    } else {     // int32 layout
        const int* mi = (const int*)mask;
        for (int s = threadIdx.x; s < SEQ; s += 256) {
            c0 += (mi[s] != 0);
            c1 += (mi[SEQ + s] != 0);
        }
    }
    atomicAdd(&cnt[0], c0);
    atomicAdd(&cnt[1], c1);
    __syncthreads();
    if (threadIdx.x == 0) {
        lens[0] = SEQ - cnt[0];
        lens[1] = SEQ - cnt[1];
    }
}

// -------- QKV GEMM: split outputs: Qd natural, Kd per-head dense, Vp tiled-transposed --
__global__ __launch_bounds__(256) void gemm_qkv(const __bf16* __restrict__ A,
                                                const __bf16* __restrict__ Bw,
                                                const float* __restrict__ bias,
                                                __bf16* __restrict__ Qd,
                                                __bf16* __restrict__ Kd,
                                                __bf16* __restrict__ Vp) {
    const int K = 768;
    __shared__ __align__(16) __bf16 As[128][64];
    __shared__ __align__(16) __bf16 Bs[128][64];
    const int tid = threadIdx.x;
    const int wave = tid >> 6, lane = tid & 63;
    const int bm = blockIdx.x * 128, bn = blockIdx.y * 128;
    const int wr = (wave >> 1) * 64, wc = (wave & 1) * 64;
    const int l15 = lane & 15, lg = lane >> 4;
    const int rsub = lane >> 3;
    const int csub = (((lane & 7) ^ rsub) * 8);
    const int rswz = (l15 & 7) * 8;

    f32x4 acc[4][4] = {};

    for (int kt = 0; kt < K; kt += 64) {
#pragma unroll
        for (int it = 0; it < 4; ++it) {
            int c = it * 4 + wave;
            int row = c * 8 + rsub;
            g2l16(A + (size_t)(bm + row) * K + kt + csub, &As[0][0] + c * 512);
            g2l16(Bw + (size_t)(bn + row) * K + kt + csub, &Bs[0][0] + c * 512);
        }
        __syncthreads();
#pragma unroll
        for (int kk = 0; kk < 2; ++kk) {
            bf16x8 af[4], bfr[4];
            const int col = (kk * 32 + lg * 8) ^ rswz;
#pragma unroll
            for (int m = 0; m < 4; ++m)
                af[m] = *(const bf16x8*)(&As[0][0] + (wr + m * 16 + l15) * 64 + col);
#pragma unroll
            for (int n = 0; n < 4; ++n)
                bfr[n] = *(const bf16x8*)(&Bs[0][0] + (wc + n * 16 + l15) * 64 + col);
#pragma unroll
            for (int m = 0; m < 4; ++m)
#pragma unroll
                for (int n = 0; n < 4; ++n)
                    acc[m][n] = __builtin_amdgcn_mfma_f32_16x16x32_bf16(af[m], bfr[n], acc[m][n], 0, 0, 0);
        }
        __syncthreads();
    }

#pragma unroll
    for (int n = 0; n < 4; ++n) {
        int col = bn + wc + n * 16 + l15;
        float bv = bias[col];
#pragma unroll
        for (int m = 0; m < 4; ++m) {
#pragma unroll
            for (int j = 0; j < 4; ++j) {
                int row = bm + wr + m * 16 + lg * 4 + j;
                __bf16 v = (__bf16)(acc[m][n][j] + bv);
                if (bn < 768) {
                    Qd[(size_t)row * 768 + col] = v;
                } else if (bn < 1536) {
                    int kc = col - 768;
                    int hh = kc >> 6, dh = kc & 63;
                    int bb = row >> 11, key = row & 2047;
                    Kd[(size_t)(bb * NH + hh) * 131072 + key * 64 + dh] = v;
                } else {
                    int vc = col - 1536;
                    int hh = vc >> 6, dh = vc & 63;
                    int bb = row >> 11, key = row & 2047;
                    Vp[(size_t)(bb * NH + hh) * 131072 + (key >> 6) * 4096 + dh * 64 + (key & 63)] = v;
                }
            }
        }
    }
}

// ---------------- out-projection GEMM (validated round 3) ----------------
__global__ __launch_bounds__(256) void gemm_out(const __bf16* __restrict__ A,
                                                const __bf16* __restrict__ Bw,
                                                const float* __restrict__ bias,
                                                float* __restrict__ Cout,
                                                int M, int N, int K) {
    __shared__ __align__(16) __bf16 As[128][64];
    __shared__ __align__(16) __bf16 Bs[128][64];
    const int tid = threadIdx.x;
    const int wave = tid >> 6, lane = tid & 63;
    const int bm = blockIdx.x * 128, bn = blockIdx.y * 128;
    const int wr = (wave >> 1) * 64, wc = (wave & 1) * 64;
    const int l15 = lane & 15, lg = lane >> 4;
    const int rsub = lane >> 3;
    const int csub = (((lane & 7) ^ rsub) * 8);
    const int rswz = (l15 & 7) * 8;

    f32x4 acc[4][4] = {};

    for (int kt = 0; kt < K; kt += 64) {
#pragma unroll
        for (int it = 0; it < 4; ++it) {
            int c = it * 4 + wave;
            int row = c * 8 + rsub;
            g2l16(A + (size_t)(bm + row) * K + kt + csub, &As[0][0] + c * 512);
            g2l16(Bw + (size_t)(bn + row) * K + kt + csub, &Bs[0][0] + c * 512);
        }
        __syncthreads();
#pragma unroll
        for (int kk = 0; kk < 2; ++kk) {
            bf16x8 af[4], bfr[4];
            const int col = (kk * 32 + lg * 8) ^ rswz;
#pragma unroll
            for (int m = 0; m < 4; ++m)
                af[m] = *(const bf16x8*)(&As[0][0] + (wr + m * 16 + l15) * 64 + col);
#pragma unroll
            for (int n = 0; n < 4; ++n)
                bfr[n] = *(const bf16x8*)(&Bs[0][0] + (wc + n * 16 + l15) * 64 + col);
#pragma unroll
            for (int m = 0; m < 4; ++m)
#pragma unroll
                for (int n = 0; n < 4; ++n)
                    acc[m][n] = __builtin_amdgcn_mfma_f32_16x16x32_bf16(af[m], bfr[n], acc[m][n], 0, 0, 0);
        }
        __syncthreads();
    }

#pragma unroll
    for (int n = 0; n < 4; ++n) {
        int col = bn + wc + n * 16 + l15;
        float bv = bias[col];
#pragma unroll
        for (int m = 0; m < 4; ++m) {
#pragma unroll
            for (int j = 0; j < 4; ++j) {
                int row = bm + wr + m * 16 + lg * 4 + j;
                Cout[(size_t)row * N + col] = acc[m][n][j] + bv;
            }
        }
    }
}

// ------- flash attention: 3-stage pipeline with DOUBLE-BUFFERED K (race-free) ---------
// 128-thread blocks (2 independent waves, same bh, adjacent-heavy p). Iteration t:
// issue QK(t+1) from buffer X, then K-load(t+2) into the OTHER buffer (last read one
// full iteration ago -> no VMEM-write-vs-inflight-MFMA-read WAR hazard), then V-load(t)
// + softmax(t) on the VALU covering the latencies, then PV(t). Shuffle-free P->PV
// (permuted K rows), folded scale, static-max softmax, dense Kd / tiled Vp layouts.
__global__ __launch_bounds__(128) void attn_kernel(const __bf16* __restrict__ Qd,
                                                   const __bf16* __restrict__ Kd,
                                                   const int* __restrict__ lens,
                                                   const __bf16* __restrict__ Vp,
                                                   __bf16* __restrict__ Out) {
    const int lane = threadIdx.x & 63, wave = threadIdx.x >> 6;
    const int l15 = lane & 15, lg = lane >> 4;
    const int blk = blockIdx.x;
    const int xcd = blk & 7, idx = blk >> 3;   // idx 0..95
    const int hl = idx % 3, pd2 = idx / 3;     // pd2 0..31
    const int p = 63 - (pd2 * 2 + wave);       // heavy first; waves share bh
    const int bh = xcd * 3 + hl;
    const int b = bh / NH, h = bh % NH;
    const int len = lens[b];
    const int q0 = p * 32;

    // permuted K row for this lane: prow = (l15>>2)*8 + (l15&3)
    const int prow = ((l15 >> 2) << 3) + (l15 & 3);
    const __bf16* kbase = Kd + (size_t)bh * 131072 + prow * 64 + lg * 8;
    const __bf16* vbase = Vp + (size_t)bh * 131072 + l15 * 64 + lg * 8;

    // Q fragments (B-operand) for both subtiles
    bf16x8 qf[2][2];
    int qcap[2];
#pragma unroll
    for (int m = 0; m < 2; ++m) {
        const __bf16* qp_ = Qd + (size_t)(b * SEQ + q0 + m * 16 + l15) * DMODEL + h * DHEAD + lg * 8;
        qf[m][0] = *(const bf16x8*)qp_;
        qf[m][1] = *(const bf16x8*)(qp_ + 32);
        int myq = q0 + m * 16 + l15;
        qcap[m] = (len - 1 < myq) ? (len - 1) : myq;
    }

    int kmax = q0 + 32;
    if (len < kmax) kmax = len;
    const int nt = (kmax + 63) >> 6;

    f32x4 accO[2][4] = {};
    float l_part[2] = {0.f, 0.f};

    bf16x8 kA[2][4], kB[2][4];     // double-buffered K fragments
    f32x4 scA[2][4], scB[2][4];    // double-buffered score tiles

    auto kload = [&](bf16x8(&kf)[2][4], int kt) {
        const int k0 = kt * 64;
#pragma unroll
        for (int n = 0; n < 4; ++n) {
            const int roff = (k0 + ((n >> 1) << 5) + ((n & 1) << 2)) * 64;
#pragma unroll
            for (int kkd = 0; kkd < 2; ++kkd)
                kf[kkd][n] = *(const bf16x8*)(kbase + roff + kkd * 32);
        }
    };

    auto qk = [&](f32x4(&sc)[2][4], bf16x8(&kf)[2][4]) {
        __builtin_amdgcn_s_setprio(1);
#pragma unroll
        for (int m = 0; m < 2; ++m)
#pragma unroll
            for (int n = 0; n < 4; ++n) {
                sc[m][n] = __builtin_amdgcn_mfma_f32_16x16x32_bf16(kf[0][n], qf[m][0],
                                                                   f32x4{0.f, 0.f, 0.f, 0.f}, 0, 0, 0);
                sc[m][n] = __builtin_amdgcn_mfma_f32_16x16x32_bf16(kf[1][n], qf[m][1], sc[m][n], 0, 0, 0);
            }
        __builtin_amdgcn_s_setprio(0);
    };

    auto step = [&](f32x4(&sc)[2][4], int kt) {
        const int k0 = kt * 64;
        // V fragments for this tile (issued before softmax; consumed after)
        const __bf16* vt = vbase + kt * 4096;
        bf16x8 vf[2][4];
#pragma unroll
        for (int kk = 0; kk < 2; ++kk)
#pragma unroll
            for (int n = 0; n < 4; ++n)
                vf[kk][n] = *(const bf16x8*)(vt + n * 1024 + kk * 32);

        bf16x8 pa[2][2];
#pragma unroll
        for (int m = 0; m < 2; ++m) {
            const bool full = (k0 + 63 <= q0 + m * 16) && (k0 + 63 < len);
            float psum = 0.f;
            unsigned pk[4][2];
#pragma unroll
            for (int n = 0; n < 4; ++n) {
                const int keyb = k0 + ((n >> 1) << 5) + lg * 8 + ((n & 1) << 2);
                float pv[4];
#pragma unroll
                for (int j = 0; j < 4; ++j) {
                    float e = exp2f(sc[m][n][j]);
                    if (!full) e = (keyb + j <= qcap[m]) ? e : 0.f;
                    pv[j] = e;
                }
                psum += (pv[0] + pv[1]) + (pv[2] + pv[3]);
                pk[n][0] = pack_bf16(pv[0], pv[1]);
                pk[n][1] = pack_bf16(pv[2], pv[3]);
            }
            l_part[m] += psum;

            uint4 u0 = {pk[0][0], pk[0][1], pk[1][0], pk[1][1]};
            uint4 u1 = {pk[2][0], pk[2][1], pk[3][0], pk[3][1]};
            pa[m][0] = __builtin_bit_cast(bf16x8, u0);
            pa[m][1] = __builtin_bit_cast(bf16x8, u1);
        }

        __builtin_amdgcn_s_setprio(1);
#pragma unroll
        for (int m = 0; m < 2; ++m)
#pragma unroll
            for (int kk = 0; kk < 2; ++kk)
#pragma unroll
                for (int n = 0; n < 4; ++n)
                    accO[m][n] = __builtin_amdgcn_mfma_f32_16x16x32_bf16(pa[m][kk], vf[kk][n], accO[m][n], 0, 0, 0);
        __builtin_amdgcn_s_setprio(0);
    };

    // pipeline prologue: S(0) from kA; K(1) -> kB
    kload(kA, 0);
    qk(scA, kA);
    if (nt > 1) kload(kB, 1);

    int t = 0;
    for (;;) {
        {   // current scores in scA; next K in kB; kA is free
            const bool hasN = (t + 1 < nt);
            if (hasN) qk(scB, kB);             // QK(t+1) on matrix pipe
            if (t + 2 < nt) kload(kA, t + 2);  // prefetch into the free buffer
            step(scA, t);                      // V-load, softmax (covers latency), PV
            ++t;
            if (!hasN) break;
        }
        {   // current scores in scB; next K in kA; kB is free
            const bool hasN = (t + 1 < nt);
            if (hasN) qk(scA, kA);
            if (t + 2 < nt) kload(kB, t + 2);
            step(scB, t);
            ++t;
            if (!hasN) break;
        }
    }

    // epilogue: reduce l across the 4 lane-groups, normalize, store
#pragma unroll
    for (int m = 0; m < 2; ++m) {
        float lp = l_part[m];
        lp += __shfl_xor(lp, 16);
        lp += __shfl_xor(lp, 32);
        float inv = 1.0f / lp;
        float inv_j[4];
#pragma unroll
        for (int j = 0; j < 4; ++j) inv_j[j] = __shfl(inv, lg * 4 + j);
#pragma unroll
        for (int n = 0; n < 4; ++n)
#pragma unroll
            for (int j = 0; j < 4; ++j) {
                int q = q0 + m * 16 + lg * 4 + j;
                Out[(size_t)(b * SEQ + q) * DMODEL + h * DHEAD + n * 16 + l15] =
                    (__bf16)(accO[m][n][j] * inv_j[j]);
            }
    }
}

extern "C" void kernel_launch(void* const* d_in, const int* in_sizes, int n_in,
                              void* d_out, int out_size, void* d_ws, size_t ws_size,
                              hipStream_t stream) {
    const float* query = (const float*)d_in[0];
    const unsigned char* mask = (const unsigned char*)d_in[1];
    const float* w_qkv = (const float*)d_in[2];
    const float* b_qkv = (const float*)d_in[3];
    const float* w_out = (const float*)d_in[4];
    const float* b_out = (const float*)d_in[5];
    float* out = (float*)d_out;

    if (ws_size < 36200448ull) return;
    char* p = (char*)d_ws;
    int* lens = (int*)p;        p += 256;
    float* bqs = (float*)p;     p += 2304 * 4 + 256;
    __bf16* Xb = (__bf16*)p;    p += (size_t)4096 * 768 * 2;
    __bf16* Wqb = (__bf16*)p;   p += (size_t)2304 * 768 * 2;
    __bf16* Wob = (__bf16*)p;   p += (size_t)768 * 768 * 2;
    __bf16* Qd = (__bf16*)p;    p += (size_t)4096 * 768 * 2;
    __bf16* Kd = (__bf16*)p;    p += (size_t)4096 * 768 * 2;
    __bf16* Vp = (__bf16*)p;    p += (size_t)4096 * 768 * 2;
    __bf16* AOb = (__bf16*)p;   p += (size_t)4096 * 768 * 2;

    lens_kernel<<<1, 256, 0, stream>>>(mask, b_qkv, bqs, lens);
    cvt3_kernel<<<(XQ + WQQ + WOQ) / 256, 256, 0, stream>>>(query, w_qkv, w_out, Xb, Wqb, Wob);

    // QKV projection with split outputs (Q pre-scaled; K dense per-head; V tiled-transposed)
    gemm_qkv<<<dim3(32, 18), 256, 0, stream>>>(Xb, Wqb, bqs, Qd, Kd, Vp);
    // attention: 768 blocks x 2 pipelined waves
    attn_kernel<<<768, 128, 0, stream>>>(Qd, Kd, lens, Vp, AOb);
    // output projection: [4096,768] @ [768,768]^T -> f32 d_out
    gemm_out<<<dim3(32, 6), 256, 0, stream>>>(AOb, Wob, b_out, out, 4096, 768, 768);
}

// Round 15
// 134.769 us; speedup vs baseline: 1.0748x; 1.0015x over previous
//
#include <hip/hip_runtime.h>

#define BATCH 2
#define SEQ 2048
#define DMODEL 768
#define NH 12
#define DHEAD 64
#define D3 (3 * DMODEL)  // 2304

typedef float f32x4 __attribute__((ext_vector_type(4)));
typedef __bf16 bf16x8 __attribute__((ext_vector_type(8)));
typedef __bf16 bf16x4 __attribute__((ext_vector_type(4)));

#define NEG_INF (-__builtin_inff())
#define SCL 0.18033688011112042f  // (1/sqrt(64)) * log2(e), folded into W_q/b_q

__device__ __forceinline__ void g2l16(const void* g, void* l) {
    __builtin_amdgcn_global_load_lds(
        (const __attribute__((address_space(1))) void*)g,
        (__attribute__((address_space(3))) void*)l,
        16, 0, 0);
}

__device__ __forceinline__ unsigned pack_bf16(float lo, float hi) {
    unsigned a = __builtin_bit_cast(unsigned short, (__bf16)lo);
    unsigned b = __builtin_bit_cast(unsigned short, (__bf16)hi);
    return a | (b << 16);
}

// ---------------- fused f32 -> bf16 convert (counts in float4 units) ----------------
#define XQ 786432   // 2*2048*768 / 4
#define WQQ 442368  // 2304*768 / 4
#define WOQ 147456  // 768*768 / 4
#define WQROWS 147456  // float4 idx bound for w_qkv rows < 768
__global__ __launch_bounds__(256) void cvt3_kernel(const float* __restrict__ X,
                                                   const float* __restrict__ Wq,
                                                   const float* __restrict__ Wo,
                                                   __bf16* __restrict__ Xb,
                                                   __bf16* __restrict__ Wqb,
                                                   __bf16* __restrict__ Wob) {
    int i = blockIdx.x * 256 + threadIdx.x;
    const float* s; __bf16* d; int k;
    float scl = 1.0f;
    if (i < XQ)            { s = X;  d = Xb;  k = i; }
    else if (i < XQ + WQQ) { s = Wq; d = Wqb; k = i - XQ; if (k < WQROWS) scl = SCL; }
    else                   { s = Wo; d = Wob; k = i - XQ - WQQ; }
    float4 v = ((const float4*)s)[k];
    bf16x4 o;
    o[0] = (__bf16)(v.x * scl); o[1] = (__bf16)(v.y * scl);
    o[2] = (__bf16)(v.z * scl); o[3] = (__bf16)(v.w * scl);
    ((bf16x4*)d)[k] = o;
}

// ---------------- padding mask -> lengths; also emit scaled b_qkv copy ----------------
__global__ __launch_bounds__(256) void lens_kernel(const unsigned char* __restrict__ mask,
                                                   const float* __restrict__ bq,
                                                   float* __restrict__ bqs,
                                                   int* __restrict__ lens) {
    __shared__ int nz_s;
    __shared__ int cnt[2];
    if (threadIdx.x == 0) { nz_s = 0; cnt[0] = 0; cnt[1] = 0; }
    __syncthreads();
    for (int i = threadIdx.x; i < D3; i += 256)
        bqs[i] = bq[i] * (i < DMODEL ? SCL : 1.0f);
    uint4 mv = ((const uint4*)mask)[threadIdx.x];  // covers bytes [0,4096)
    if (mv.x | mv.y | mv.z | mv.w) nz_s = 1;
    __syncthreads();
    int c0 = 0, c1 = 0;
    if (nz_s) {  // bool layout
        for (int s = threadIdx.x; s < SEQ; s += 256) {
            c0 += (mask[s] != 0);
            c1 += (mask[SEQ + s] != 0);
        }
    } else {     // int32 layout
        const int* mi = (const int*)mask;
        for (int s = threadIdx.x; s < SEQ; s += 256) {
            c0 += (mi[s] != 0);
            c1 += (mi[SEQ + s] != 0);
        }
    }
    atomicAdd(&cnt[0], c0);
    atomicAdd(&cnt[1], c1);
    __syncthreads();
    if (threadIdx.x == 0) {
        lens[0] = SEQ - cnt[0];
        lens[1] = SEQ - cnt[1];
    }
}

// -------- QKV GEMM: split outputs: Qd natural, Kd per-head dense, Vp tiled-transposed --
__global__ __launch_bounds__(256) void gemm_qkv(const __bf16* __restrict__ A,
                                                const __bf16* __restrict__ Bw,
                                                const float* __restrict__ bias,
                                                __bf16* __restrict__ Qd,
                                                __bf16* __restrict__ Kd,
                                                __bf16* __restrict__ Vp) {
    const int K = 768;
    __shared__ __align__(16) __bf16 As[128][64];
    __shared__ __align__(16) __bf16 Bs[128][64];
    const int tid = threadIdx.x;
    const int wave = tid >> 6, lane = tid & 63;
    const int bm = blockIdx.x * 128, bn = blockIdx.y * 128;
    const int wr = (wave >> 1) * 64, wc = (wave & 1) * 64;
    const int l15 = lane & 15, lg = lane >> 4;
    const int rsub = lane >> 3;
    const int csub = (((lane & 7) ^ rsub) * 8);
    const int rswz = (l15 & 7) * 8;

    f32x4 acc[4][4] = {};

    for (int kt = 0; kt < K; kt += 64) {
#pragma unroll
        for (int it = 0; it < 4; ++it) {
            int c = it * 4 + wave;
            int row = c * 8 + rsub;
            g2l16(A + (size_t)(bm + row) * K + kt + csub, &As[0][0] + c * 512);
            g2l16(Bw + (size_t)(bn + row) * K + kt + csub, &Bs[0][0] + c * 512);
        }
        __syncthreads();
#pragma unroll
        for (int kk = 0; kk < 2; ++kk) {
            bf16x8 af[4], bfr[4];
            const int col = (kk * 32 + lg * 8) ^ rswz;
#pragma unroll
            for (int m = 0; m < 4; ++m)
                af[m] = *(const bf16x8*)(&As[0][0] + (wr + m * 16 + l15) * 64 + col);
#pragma unroll
            for (int n = 0; n < 4; ++n)
                bfr[n] = *(const bf16x8*)(&Bs[0][0] + (wc + n * 16 + l15) * 64 + col);
#pragma unroll
            for (int m = 0; m < 4; ++m)
#pragma unroll
                for (int n = 0; n < 4; ++n)
                    acc[m][n] = __builtin_amdgcn_mfma_f32_16x16x32_bf16(af[m], bfr[n], acc[m][n], 0, 0, 0);
        }
        __syncthreads();
    }

#pragma unroll
    for (int n = 0; n < 4; ++n) {
        int col = bn + wc + n * 16 + l15;
        float bv = bias[col];
#pragma unroll
        for (int m = 0; m < 4; ++m) {
#pragma unroll
            for (int j = 0; j < 4; ++j) {
                int row = bm + wr + m * 16 + lg * 4 + j;
                __bf16 v = (__bf16)(acc[m][n][j] + bv);
                if (bn < 768) {
                    Qd[(size_t)row * 768 + col] = v;
                } else if (bn < 1536) {
                    int kc = col - 768;
                    int hh = kc >> 6, dh = kc & 63;
                    int bb = row >> 11, key = row & 2047;
                    Kd[(size_t)(bb * NH + hh) * 131072 + key * 64 + dh] = v;
                } else {
                    int vc = col - 1536;
                    int hh = vc >> 6, dh = vc & 63;
                    int bb = row >> 11, key = row & 2047;
                    Vp[(size_t)(bb * NH + hh) * 131072 + (key >> 6) * 4096 + dh * 64 + (key & 63)] = v;
                }
            }
        }
    }
}

// ---------------- out-projection GEMM (validated round 3) ----------------
__global__ __launch_bounds__(256) void gemm_out(const __bf16* __restrict__ A,
                                                const __bf16* __restrict__ Bw,
                                                const float* __restrict__ bias,
                                                float* __restrict__ Cout,
                                                int M, int N, int K) {
    __shared__ __align__(16) __bf16 As[128][64];
    __shared__ __align__(16) __bf16 Bs[128][64];
    const int tid = threadIdx.x;
    const int wave = tid >> 6, lane = tid & 63;
    const int bm = blockIdx.x * 128, bn = blockIdx.y * 128;
    const int wr = (wave >> 1) * 64, wc = (wave & 1) * 64;
    const int l15 = lane & 15, lg = lane >> 4;
    const int rsub = lane >> 3;
    const int csub = (((lane & 7) ^ rsub) * 8);
    const int rswz = (l15 & 7) * 8;

    f32x4 acc[4][4] = {};

    for (int kt = 0; kt < K; kt += 64) {
#pragma unroll
        for (int it = 0; it < 4; ++it) {
            int c = it * 4 + wave;
            int row = c * 8 + rsub;
            g2l16(A + (size_t)(bm + row) * K + kt + csub, &As[0][0] + c * 512);
            g2l16(Bw + (size_t)(bn + row) * K + kt + csub, &Bs[0][0] + c * 512);
        }
        __syncthreads();
#pragma unroll
        for (int kk = 0; kk < 2; ++kk) {
            bf16x8 af[4], bfr[4];
            const int col = (kk * 32 + lg * 8) ^ rswz;
#pragma unroll
            for (int m = 0; m < 4; ++m)
                af[m] = *(const bf16x8*)(&As[0][0] + (wr + m * 16 + l15) * 64 + col);
#pragma unroll
            for (int n = 0; n < 4; ++n)
                bfr[n] = *(const bf16x8*)(&Bs[0][0] + (wc + n * 16 + l15) * 64 + col);
#pragma unroll
            for (int m = 0; m < 4; ++m)
#pragma unroll
                for (int n = 0; n < 4; ++n)
                    acc[m][n] = __builtin_amdgcn_mfma_f32_16x16x32_bf16(af[m], bfr[n], acc[m][n], 0, 0, 0);
        }
        __syncthreads();
    }

#pragma unroll
    for (int n = 0; n < 4; ++n) {
        int col = bn + wc + n * 16 + l15;
        float bv = bias[col];
#pragma unroll
        for (int m = 0; m < 4; ++m) {
#pragma unroll
            for (int j = 0; j < 4; ++j) {
                int row = bm + wr + m * 16 + lg * 4 + j;
                Cout[(size_t)row * N + col] = acc[m][n][j] + bv;
            }
        }
    }
}

// ------- flash attention: pipeline with V-before-K issue order (vmcnt-friendly) -------
// Iteration t: V-load(t) -> QK(t+1) [waits vmcnt(8) on 1-iter-old K buf: free] ->
// K-load(t+2) into free buffer -> softmax(t) on VALU -> PV(t) [waits vmcnt(8): V
// drained under softmax cover; K(t+2) STAYS IN FLIGHT]. No vmcnt(0) in steady state.
// V double-buffered (WAR safety vs in-flight PV MFMAs). Shuffle-free P->PV (permuted
// K rows), folded scale, static-max softmax, dense Kd / tiled Vp layouts.
__global__ __launch_bounds__(128) void attn_kernel(const __bf16* __restrict__ Qd,
                                                   const __bf16* __restrict__ Kd,
                                                   const int* __restrict__ lens,
                                                   const __bf16* __restrict__ Vp,
                                                   __bf16* __restrict__ Out) {
    const int lane = threadIdx.x & 63, wave = threadIdx.x >> 6;
    const int l15 = lane & 15, lg = lane >> 4;
    const int blk = blockIdx.x;
    const int xcd = blk & 7, idx = blk >> 3;   // idx 0..95
    const int hl = idx % 3, pd2 = idx / 3;     // pd2 0..31
    const int p = 63 - (pd2 * 2 + wave);       // heavy first; waves share bh
    const int bh = xcd * 3 + hl;
    const int b = bh / NH, h = bh % NH;
    const int len = lens[b];
    const int q0 = p * 32;

    // permuted K row for this lane: prow = (l15>>2)*8 + (l15&3)
    const int prow = ((l15 >> 2) << 3) + (l15 & 3);
    const __bf16* kbase = Kd + (size_t)bh * 131072 + prow * 64 + lg * 8;
    const __bf16* vbase = Vp + (size_t)bh * 131072 + l15 * 64 + lg * 8;

    // Q fragments (B-operand) for both subtiles
    bf16x8 qf[2][2];
    int qcap[2];
#pragma unroll
    for (int m = 0; m < 2; ++m) {
        const __bf16* qp_ = Qd + (size_t)(b * SEQ + q0 + m * 16 + l15) * DMODEL + h * DHEAD + lg * 8;
        qf[m][0] = *(const bf16x8*)qp_;
        qf[m][1] = *(const bf16x8*)(qp_ + 32);
        int myq = q0 + m * 16 + l15;
        qcap[m] = (len - 1 < myq) ? (len - 1) : myq;
    }

    int kmax = q0 + 32;
    if (len < kmax) kmax = len;
    const int nt = (kmax + 63) >> 6;

    f32x4 accO[2][4] = {};
    float l_part[2] = {0.f, 0.f};

    bf16x8 kA[2][4], kB[2][4];     // double-buffered K fragments
    bf16x8 vfA[2][4], vfB[2][4];   // double-buffered V fragments
    f32x4 scA[2][4], scB[2][4];    // double-buffered score tiles

    auto kload = [&](bf16x8(&kf)[2][4], int kt) {
        const int k0 = kt * 64;
#pragma unroll
        for (int n = 0; n < 4; ++n) {
            const int roff = (k0 + ((n >> 1) << 5) + ((n & 1) << 2)) * 64;
#pragma unroll
            for (int kkd = 0; kkd < 2; ++kkd)
                kf[kkd][n] = *(const bf16x8*)(kbase + roff + kkd * 32);
        }
    };

    auto vload = [&](bf16x8(&vf)[2][4], int kt) {
        const __bf16* vt = vbase + kt * 4096;
#pragma unroll
        for (int kk = 0; kk < 2; ++kk)
#pragma unroll
            for (int n = 0; n < 4; ++n)
                vf[kk][n] = *(const bf16x8*)(vt + n * 1024 + kk * 32);
    };

    auto qk = [&](f32x4(&sc)[2][4], bf16x8(&kf)[2][4]) {
        __builtin_amdgcn_s_setprio(1);
#pragma unroll
        for (int m = 0; m < 2; ++m)
#pragma unroll
            for (int n = 0; n < 4; ++n) {
                sc[m][n] = __builtin_amdgcn_mfma_f32_16x16x32_bf16(kf[0][n], qf[m][0],
                                                                   f32x4{0.f, 0.f, 0.f, 0.f}, 0, 0, 0);
                sc[m][n] = __builtin_amdgcn_mfma_f32_16x16x32_bf16(kf[1][n], qf[m][1], sc[m][n], 0, 0, 0);
            }
        __builtin_amdgcn_s_setprio(0);
    };

    auto step = [&](f32x4(&sc)[2][4], bf16x8(&vf)[2][4], int kt) {
        const int k0 = kt * 64;
        bf16x8 pa[2][2];
#pragma unroll
        for (int m = 0; m < 2; ++m) {
            const bool full = (k0 + 63 <= q0 + m * 16) && (k0 + 63 < len);
            float psum = 0.f;
            unsigned pk[4][2];
#pragma unroll
            for (int n = 0; n < 4; ++n) {
                const int keyb = k0 + ((n >> 1) << 5) + lg * 8 + ((n & 1) << 2);
                float pv[4];
#pragma unroll
                for (int j = 0; j < 4; ++j) {
                    float e = exp2f(sc[m][n][j]);
                    if (!full) e = (keyb + j <= qcap[m]) ? e : 0.f;
                    pv[j] = e;
                }
                psum += (pv[0] + pv[1]) + (pv[2] + pv[3]);
                pk[n][0] = pack_bf16(pv[0], pv[1]);
                pk[n][1] = pack_bf16(pv[2], pv[3]);
            }
            l_part[m] += psum;

            uint4 u0 = {pk[0][0], pk[0][1], pk[1][0], pk[1][1]};
            uint4 u1 = {pk[2][0], pk[2][1], pk[3][0], pk[3][1]};
            pa[m][0] = __builtin_bit_cast(bf16x8, u0);
            pa[m][1] = __builtin_bit_cast(bf16x8, u1);
        }

        __builtin_amdgcn_s_setprio(1);
#pragma unroll
        for (int m = 0; m < 2; ++m)
#pragma unroll
            for (int kk = 0; kk < 2; ++kk)
#pragma unroll
                for (int n = 0; n < 4; ++n)
                    accO[m][n] = __builtin_amdgcn_mfma_f32_16x16x32_bf16(pa[m][kk], vf[kk][n], accO[m][n], 0, 0, 0);
        __builtin_amdgcn_s_setprio(0);
    };

    // pipeline prologue: S(0) from kA; K(1) -> kB
    kload(kA, 0);
    qk(scA, kA);
    if (nt > 1) kload(kB, 1);

    int t = 0;
    for (;;) {
        {   // scores in scA; next K in kB; kA free; V -> vfA
            const bool hasN = (t + 1 < nt);
            vload(vfA, t);                     // V FIRST (oldest outstanding)
            if (hasN) qk(scB, kB);             // vmcnt(8): kB is 1 iter old (free)
            if (t + 2 < nt) kload(kA, t + 2);  // prefetch; stays in flight thru PV
            step(scA, vfA, t);                 // softmax covers V; PV waits vmcnt(8)
            ++t;
            if (!hasN) break;
        }
        {   // scores in scB; next K in kA; kB free; V -> vfB
            const bool hasN = (t + 1 < nt);
            vload(vfB, t);
            if (hasN) qk(scA, kA);
            if (t + 2 < nt) kload(kB, t + 2);
            step(scB, vfB, t);
            ++t;
            if (!hasN) break;
        }
    }

    // epilogue: reduce l across the 4 lane-groups, normalize, store
#pragma unroll
    for (int m = 0; m < 2; ++m) {
        float lp = l_part[m];
        lp += __shfl_xor(lp, 16);
        lp += __shfl_xor(lp, 32);
        float inv = 1.0f / lp;
        float inv_j[4];
#pragma unroll
        for (int j = 0; j < 4; ++j) inv_j[j] = __shfl(inv, lg * 4 + j);
#pragma unroll
        for (int n = 0; n < 4; ++n)
#pragma unroll
            for (int j = 0; j < 4; ++j) {
                int q = q0 + m * 16 + lg * 4 + j;
                Out[(size_t)(b * SEQ + q) * DMODEL + h * DHEAD + n * 16 + l15] =
                    (__bf16)(accO[m][n][j] * inv_j[j]);
            }
    }
}

extern "C" void kernel_launch(void* const* d_in, const int* in_sizes, int n_in,
                              void* d_out, int out_size, void* d_ws, size_t ws_size,
                              hipStream_t stream) {
    const float* query = (const float*)d_in[0];
    const unsigned char* mask = (const unsigned char*)d_in[1];
    const float* w_qkv = (const float*)d_in[2];
    const float* b_qkv = (const float*)d_in[3];
    const float* w_out = (const float*)d_in[4];
    const float* b_out = (const float*)d_in[5];
    float* out = (float*)d_out;

    if (ws_size < 36200448ull) return;
    char* p = (char*)d_ws;
    int* lens = (int*)p;        p += 256;
    float* bqs = (float*)p;     p += 2304 * 4 + 256;
    __bf16* Xb = (__bf16*)p;    p += (size_t)4096 * 768 * 2;
    __bf16* Wqb = (__bf16*)p;   p += (size_t)2304 * 768 * 2;
    __bf16* Wob = (__bf16*)p;   p += (size_t)768 * 768 * 2;
    __bf16* Qd = (__bf16*)p;    p += (size_t)4096 * 768 * 2;
    __bf16* Kd = (__bf16*)p;    p += (size_t)4096 * 768 * 2;
    __bf16* Vp = (__bf16*)p;    p += (size_t)4096 * 768 * 2;
    __bf16* AOb = (__bf16*)p;   p += (size_t)4096 * 768 * 2;

    lens_kernel<<<1, 256, 0, stream>>>(mask, b_qkv, bqs, lens);
    cvt3_kernel<<<(XQ + WQQ + WOQ) / 256, 256, 0, stream>>>(query, w_qkv, w_out, Xb, Wqb, Wob);

    // QKV projection with split outputs (Q pre-scaled; K dense per-head; V tiled-transposed)
    gemm_qkv<<<dim3(32, 18), 256, 0, stream>>>(Xb, Wqb, bqs, Qd, Kd, Vp);
    // attention: 768 blocks x 2 pipelined waves
    attn_kernel<<<768, 128, 0, stream>>>(Qd, Kd, lens, Vp, AOb);
    // output projection: [4096,768] @ [768,768]^T -> f32 d_out
    gemm_out<<<dim3(32, 6), 256, 0, stream>>>(AOb, Wob, b_out, out, 4096, 768, 768);
}